// Round 1
// baseline (449.098 us; speedup 1.0000x reference)
//
#include <hip/hip_runtime.h>
#include <float.h>

#define NN 50000
#define NE 800000
#define NG 64
#define CAP 64

typedef __attribute__((ext_vector_type(8))) _Float16 f16x8;
typedef __attribute__((ext_vector_type(4))) float f32x4;
typedef __attribute__((ext_vector_type(8))) unsigned short u16x8;
typedef unsigned int u32;
typedef unsigned short u16;

// ---------- helpers ----------
__device__ __forceinline__ unsigned f2mono(float f) {
  unsigned b = __float_as_uint(f);
  return (b & 0x80000000u) ? ~b : (b | 0x80000000u);
}
__device__ __forceinline__ float mono2f(unsigned u) {
  unsigned b = (u & 0x80000000u) ? (u & 0x7fffffffu) : ~u;
  return __uint_as_float(b);
}
// async global->LDS 16B DMA (gfx950). LDS dest must be wave-uniform base + lane*16.
__device__ __forceinline__ void gl_lds16(const void* g, void* l) {
  __builtin_amdgcn_global_load_lds((const __attribute__((address_space(1))) u32*)g,
                                   (__attribute__((address_space(3))) u32*)l, 16, 0, 0);
}

// ---------- degree count + ELL fill (ushort cols): 1 edge/thread, max TLP ----------
__global__ void k_count(const int* __restrict__ src, const int* __restrict__ dst,
                        int* __restrict__ cnt, u16* __restrict__ col) {
  int e = blockIdx.x * 256 + threadIdx.x;
  if (e >= NE) return;
  int d = dst[e];
  int s = src[e];
  if ((unsigned)d >= NN || (unsigned)s >= NN) return;
  int pos = atomicAdd(&cnt[d], 1);
  if (pos < CAP) col[d * CAP + pos] = (u16)s;
}

// dinv + pre-scaled input features xs = x * dinv[v]; also zero-init pool buffer
__global__ void k_dinv(const int* __restrict__ cnt, float* __restrict__ dinv,
                       const float* __restrict__ x, float* __restrict__ xs,
                       unsigned* __restrict__ g) {
  int v = blockIdx.x * blockDim.x + threadIdx.x;
  if (v >= NN) return;
  if (v < NG * 256) g[v] = 0u;
  float d = rsqrtf((float)cnt[v] + 1.0f);
  dinv[v] = d;
#pragma unroll
  for (int i = 0; i < 9; ++i) xs[v * 9 + i] = x[v * 9 + i] * d;
}

// ---------- fused weight split+transpose for W2,W3,W4: W[K][Nc] -> Wh/Wl[Nc][K] ----------
__device__ __forceinline__ void splitw1(const float* W, _Float16* Wh, _Float16* Wl,
                                        int i, int K, int Nc) {
  int k = i / Nc, n = i - k * Nc;
  float w = W[i];
  _Float16 h = (_Float16)w;
  _Float16 l = (_Float16)(w - (float)h);
  Wh[(size_t)n * K + k] = h;
  Wl[(size_t)n * K + k] = l;
}
__global__ void k_splitw3(const float* __restrict__ W2, const float* __restrict__ W3,
                          const float* __restrict__ W4,
                          _Float16* __restrict__ W2h, _Float16* __restrict__ W2l,
                          _Float16* __restrict__ W3h, _Float16* __restrict__ W3l,
                          _Float16* __restrict__ W4h, _Float16* __restrict__ W4l) {
  int i = blockIdx.x * 256 + threadIdx.x;
  const int n2 = 128 * 256, n3 = 256 * 256;
  if (i < n2) splitw1(W2, W2h, W2l, i, 128, 256);
  else if (i < n2 + n3) splitw1(W3, W3h, W3l, i - n2, 256, 256);
  else if (i < n2 + 2 * n3) splitw1(W4, W4h, W4l, i - n2 - n3, 256, 256);
}

// ---------- aggregation F=9: 16-lane group per node ----------
__global__ __launch_bounds__(256) void k_agg9(const float* __restrict__ xs,
                                              float* __restrict__ out,
                                              const int* __restrict__ cnt,
                                              const u16* __restrict__ col,
                                              const float* __restrict__ dinv) {
  int v = (blockIdx.x * 256 + threadIdx.x) >> 4;
  int l = threadIdx.x & 15;
  if (v >= NN) return;
  int c = cnt[v]; if (c > CAP) c = CAP;
  const u16* cl = col + (size_t)v * CAP;
  float acc = (l < 9) ? xs[v * 9 + l] : 0.0f;
  int j = 0;
  for (; j + 4 <= c; j += 4) {
    ushort4 u = *(const ushort4*)(cl + j);
    float a0 = (l < 9) ? xs[(int)u.x * 9 + l] : 0.f;
    float a1 = (l < 9) ? xs[(int)u.y * 9 + l] : 0.f;
    float a2 = (l < 9) ? xs[(int)u.z * 9 + l] : 0.f;
    float a3 = (l < 9) ? xs[(int)u.w * 9 + l] : 0.f;
    acc += (a0 + a1) + (a2 + a3);
  }
  for (; j < c; ++j) {
    int u = cl[j];
    if (l < 9) acc += xs[u * 9 + l];
  }
  if (l < 9) out[v * 9 + l] = acc * dinv[v];
}

// ---------- GEMM K=9 -> 128, + bias + relu; writes fp16 (pre-scaled by dinv) ----------
__global__ __launch_bounds__(256) void k_gemm9(const float* __restrict__ in,
                                               const float* __restrict__ W,
                                               const float* __restrict__ bias,
                                               const float* __restrict__ dinv,
                                               _Float16* __restrict__ out) {
  __shared__ float sW[9 * 128];
  __shared__ float sb[128];
  int t = threadIdx.x;
  if (t < 128) sb[t] = bias[t];
  for (int i = t; i < 9 * 128; i += 256) sW[i] = W[i];
  __syncthreads();
  int r = blockIdx.x * 2 + (t >> 7);
  int c = t & 127;
  if (r >= NN) return;
  float acc = sb[c];
#pragma unroll
  for (int i = 0; i < 9; ++i) acc += in[r * 9 + i] * sW[i * 128 + c];
  out[r * 128 + c] = (_Float16)(fmaxf(acc, 0.0f) * dinv[r]);
}

// ---------- aggregation F=128: FOUR nodes per wave, 16-lane quarters, 16B lanes ----------
// Row = 128 fp16 = 256 B = 16 x f16x8. One vmem instruction gathers 4 rows (1 KB).
// 8 loads kept in flight; tail mismatch clamps index to own row (L1-hot), adds masked.
__global__ __launch_bounds__(256) void k_agg128(const f16x8* __restrict__ h,
                                                f16x8* __restrict__ out,
                                                const int* __restrict__ cnt,
                                                const u16* __restrict__ col,
                                                const float* __restrict__ dinv) {
  int gw = (blockIdx.x * 256 + threadIdx.x) >> 6;
  int lane = threadIdx.x & 63;
  int q = lane >> 4;
  int sub = lane & 15;
  int v0 = gw * 4;
  if (v0 >= NN) return;
  int myv = v0 + q;
  int ca = cnt[v0];     ca = ca > CAP ? CAP : ca;
  int cb = cnt[v0 + 1]; cb = cb > CAP ? CAP : cb;
  int cc = cnt[v0 + 2]; cc = cc > CAP ? CAP : cc;
  int cd = cnt[v0 + 3]; cd = cd > CAP ? CAP : cd;
  int c = (q & 2) ? ((q & 1) ? cd : cc) : ((q & 1) ? cb : ca);
  int m01 = ca > cb ? ca : cb;
  int m23 = cc > cd ? cc : cd;
  int mc = m01 > m23 ? m01 : m23;
  const u16* cl = col + (size_t)myv * CAP;
  f16x8 s = h[(size_t)myv * 16 + sub];
  float acc[8];
#pragma unroll
  for (int i = 0; i < 8; ++i) acc[i] = (float)s[i];
  for (int j = 0; j < mc; j += 8) {
    u16x8 us = *(const u16x8*)(cl + j);
    f16x8 t0 = h[(size_t)((j + 0 < c) ? (int)us[0] : myv) * 16 + sub];
    f16x8 t1 = h[(size_t)((j + 1 < c) ? (int)us[1] : myv) * 16 + sub];
    f16x8 t2 = h[(size_t)((j + 2 < c) ? (int)us[2] : myv) * 16 + sub];
    f16x8 t3 = h[(size_t)((j + 3 < c) ? (int)us[3] : myv) * 16 + sub];
    f16x8 t4 = h[(size_t)((j + 4 < c) ? (int)us[4] : myv) * 16 + sub];
    f16x8 t5 = h[(size_t)((j + 5 < c) ? (int)us[5] : myv) * 16 + sub];
    f16x8 t6 = h[(size_t)((j + 6 < c) ? (int)us[6] : myv) * 16 + sub];
    f16x8 t7 = h[(size_t)((j + 7 < c) ? (int)us[7] : myv) * 16 + sub];
    if (j + 0 < c) {
#pragma unroll
      for (int i = 0; i < 8; ++i) acc[i] += (float)t0[i];
    }
    if (j + 1 < c) {
#pragma unroll
      for (int i = 0; i < 8; ++i) acc[i] += (float)t1[i];
    }
    if (j + 2 < c) {
#pragma unroll
      for (int i = 0; i < 8; ++i) acc[i] += (float)t2[i];
    }
    if (j + 3 < c) {
#pragma unroll
      for (int i = 0; i < 8; ++i) acc[i] += (float)t3[i];
    }
    if (j + 4 < c) {
#pragma unroll
      for (int i = 0; i < 8; ++i) acc[i] += (float)t4[i];
    }
    if (j + 5 < c) {
#pragma unroll
      for (int i = 0; i < 8; ++i) acc[i] += (float)t5[i];
    }
    if (j + 6 < c) {
#pragma unroll
      for (int i = 0; i < 8; ++i) acc[i] += (float)t6[i];
    }
    if (j + 7 < c) {
#pragma unroll
      for (int i = 0; i < 8; ++i) acc[i] += (float)t7[i];
    }
  }
  float d = dinv[myv];
  f16x8 o;
#pragma unroll
  for (int i = 0; i < 8; ++i) o[i] = (_Float16)(acc[i] * d);
  out[(size_t)myv * 16 + sub] = o;
}

// ---------- aggregation F=256: TWO nodes per wave, 32-lane halves, 16B lanes ----------
// Row = 256 fp16 = 512 B = 32 x f16x8. One vmem instruction gathers 2 rows (1 KB).
__global__ __launch_bounds__(256) void k_agg256(const f16x8* __restrict__ h,
                                                f16x8* __restrict__ out,
                                                const int* __restrict__ cnt,
                                                const u16* __restrict__ col,
                                                const float* __restrict__ dinv) {
  int gw = (blockIdx.x * 256 + threadIdx.x) >> 6;
  int lane = threadIdx.x & 63;
  int half = lane >> 5;
  int sub = lane & 31;
  int w0 = gw * 2;
  if (w0 >= NN) return;
  int myv = w0 + half;
  int c0 = cnt[w0];     c0 = c0 > CAP ? CAP : c0;
  int c1 = cnt[w0 + 1]; c1 = c1 > CAP ? CAP : c1;
  int c = half ? c1 : c0;
  int mc = c0 > c1 ? c0 : c1;
  const u16* cl = col + (size_t)myv * CAP;
  f16x8 s = h[(size_t)myv * 32 + sub];
  float acc[8];
#pragma unroll
  for (int i = 0; i < 8; ++i) acc[i] = (float)s[i];
  for (int j = 0; j < mc; j += 8) {
    u16x8 us = *(const u16x8*)(cl + j);
    f16x8 t0 = h[(size_t)((j + 0 < c) ? (int)us[0] : myv) * 32 + sub];
    f16x8 t1 = h[(size_t)((j + 1 < c) ? (int)us[1] : myv) * 32 + sub];
    f16x8 t2 = h[(size_t)((j + 2 < c) ? (int)us[2] : myv) * 32 + sub];
    f16x8 t3 = h[(size_t)((j + 3 < c) ? (int)us[3] : myv) * 32 + sub];
    f16x8 t4 = h[(size_t)((j + 4 < c) ? (int)us[4] : myv) * 32 + sub];
    f16x8 t5 = h[(size_t)((j + 5 < c) ? (int)us[5] : myv) * 32 + sub];
    f16x8 t6 = h[(size_t)((j + 6 < c) ? (int)us[6] : myv) * 32 + sub];
    f16x8 t7 = h[(size_t)((j + 7 < c) ? (int)us[7] : myv) * 32 + sub];
    if (j + 0 < c) {
#pragma unroll
      for (int i = 0; i < 8; ++i) acc[i] += (float)t0[i];
    }
    if (j + 1 < c) {
#pragma unroll
      for (int i = 0; i < 8; ++i) acc[i] += (float)t1[i];
    }
    if (j + 2 < c) {
#pragma unroll
      for (int i = 0; i < 8; ++i) acc[i] += (float)t2[i];
    }
    if (j + 3 < c) {
#pragma unroll
      for (int i = 0; i < 8; ++i) acc[i] += (float)t3[i];
    }
    if (j + 4 < c) {
#pragma unroll
      for (int i = 0; i < 8; ++i) acc[i] += (float)t4[i];
    }
    if (j + 5 < c) {
#pragma unroll
      for (int i = 0; i < 8; ++i) acc[i] += (float)t5[i];
    }
    if (j + 6 < c) {
#pragma unroll
      for (int i = 0; i < 8; ++i) acc[i] += (float)t6[i];
    }
    if (j + 7 < c) {
#pragma unroll
      for (int i = 0; i < 8; ++i) acc[i] += (float)t7[i];
    }
  }
  float d = dinv[myv];
  f16x8 o;
#pragma unroll
  for (int i = 0; i < 8; ++i) o[i] = (_Float16)(acc[i] * d);
  out[(size_t)myv * 32 + sub] = o;
}

// ---------- MFMA fp16 hi/lo-weight GEMM, DMA LDS staging ----------
// 1D grid 784, XCD-aware decode: the two col-blocks of the same 128 rows get
// blockIdx differing by exactly 8 -> same XCD under %8 round-robin -> A-tile
// L2 reuse. r = (b>>4)*8 + (b&7), c = (b>>3)&1.
__global__ __launch_bounds__(256) void k_mm(const _Float16* __restrict__ A,
                                            const _Float16* __restrict__ Bh,
                                            const _Float16* __restrict__ Bl,
                                            const float* __restrict__ bias,
                                            _Float16* __restrict__ C,
                                            const float* __restrict__ dinv,
                                            const int* __restrict__ batch,
                                            unsigned* __restrict__ gpool,
                                            int M, int K, int Nc, int mode) {
  __shared__ __align__(16) _Float16 Alds[128 * 64];   // 16 KB
  __shared__ __align__(16) _Float16 Bhl[128 * 64];    // 16 KB
  __shared__ __align__(16) _Float16 Bll[128 * 64];    // 16 KB
  int bid = blockIdx.x;
  int rblk = (bid >> 4) * 8 + (bid & 7);
  int cblk = (bid >> 3) & 1;
  if (rblk * 128 >= M) return;
  int rowBase = rblk * 128;
  int colBase = cblk * 128;
  int t = threadIdx.x;
  int wave = t >> 6, lane = t & 63;
  int wm = wave & 1, wn = wave >> 1;
  int lm = lane & 15;
  int q  = lane >> 4;

  int srl = wave * 32 + (lane >> 3);
  int sj  = lane & 7;
  int ssw = lane >> 3;
  int gseg = sj ^ ssw;

  f32x4 acc[4][4];
#pragma unroll
  for (int i = 0; i < 4; ++i)
#pragma unroll
    for (int j = 0; j < 4; ++j) acc[i][j] = (f32x4){0.f, 0.f, 0.f, 0.f};

  int nit = K >> 6;
  for (int it = 0; it < nit; ++it) {
    __syncthreads();
#pragma unroll
    for (int c = 0; c < 4; ++c) {
      int rl = srl + c * 8;
      int ga = rowBase + rl; if (ga > M - 1) ga = M - 1;
      int gb = colBase + rl;
      unsigned off = (unsigned)it * 64 + gseg * 8;
      int ldst = (wave * 32 + c * 8) * 64 + lane * 8;
      gl_lds16(A  + (size_t)ga * K + off, Alds + ldst);
      gl_lds16(Bh + (size_t)gb * K + off, Bhl + ldst);
      gl_lds16(Bl + (size_t)gb * K + off, Bll + ldst);
    }
    __syncthreads();

#pragma unroll
    for (int s2 = 0; s2 < 2; ++s2) {
      int slotq = ((s2 << 2) | q);
      f16x8 vbh[4], vbl[4];
#pragma unroll
      for (int ni = 0; ni < 4; ++ni) {
        int rB = wn * 64 + ni * 16 + lm;
        int slot = slotq ^ (lm & 7);
        vbh[ni] = *(const f16x8*)(Bhl + rB * 64 + slot * 8);
        vbl[ni] = *(const f16x8*)(Bll + rB * 64 + slot * 8);
      }
#pragma unroll
      for (int mi = 0; mi < 4; ++mi) {
        int rA = wm * 64 + mi * 16 + lm;
        int slot = slotq ^ (lm & 7);
        f16x8 va = *(const f16x8*)(Alds + rA * 64 + slot * 8);
#pragma unroll
        for (int ni = 0; ni < 4; ++ni) {
          acc[mi][ni] = __builtin_amdgcn_mfma_f32_16x16x32_f16(va, vbh[ni], acc[mi][ni], 0, 0, 0);
          acc[mi][ni] = __builtin_amdgcn_mfma_f32_16x16x32_f16(va, vbl[ni], acc[mi][ni], 0, 0, 0);
        }
      }
    }
  }

  int rowOff = (lane >> 4) * 4;
  if (mode == 2) {
    __syncthreads();
    unsigned* ldsPool = (unsigned*)Alds;
    for (int i = t; i < 4 * 256; i += 256) ldsPool[i] = 0u;
    __syncthreads();
    int b0 = batch[rowBase];
#pragma unroll
    for (int mi = 0; mi < 4; ++mi) {
#pragma unroll
      for (int ni = 0; ni < 4; ++ni) {
        int gc = colBase + wn * 64 + ni * 16 + lm;
        float bsv = bias[gc];
#pragma unroll
        for (int r = 0; r < 4; ++r) {
          int gr = rowBase + wm * 64 + mi * 16 + rowOff + r;
          if (gr < M) {
            float v = acc[mi][ni][r] + bsv;
            int idx = batch[gr] - b0;
            if (idx < 0) idx = 0;
            if (idx > 3) idx = 3;
            atomicMax(&ldsPool[idx * 256 + gc], f2mono(v));
          }
        }
      }
    }
    __syncthreads();
#pragma unroll
    for (int s4 = 0; s4 < 4; ++s4) {
      unsigned mv = ldsPool[s4 * 256 + t];
      int gb = b0 + s4;
      if (mv && gb < NG) atomicMax(&gpool[gb * 256 + t], mv);
    }
  } else {
#pragma unroll
    for (int mi = 0; mi < 4; ++mi) {
#pragma unroll
      for (int ni = 0; ni < 4; ++ni) {
        int gc = colBase + wn * 64 + ni * 16 + lm;
        float bsv = bias[gc];
#pragma unroll
        for (int r = 0; r < 4; ++r) {
          int gr = rowBase + wm * 64 + mi * 16 + rowOff + r;
          if (gr < M) {
            float v = fmaxf(acc[mi][ni][r] + bsv, 0.0f);
            C[(size_t)gr * Nc + gc] = (_Float16)(v * dinv[gr]);
          }
        }
      }
    }
  }
}

// ---------- dense head ----------
__global__ __launch_bounds__(256) void k_head(const unsigned* __restrict__ g,
                                              const float* __restrict__ Wl2, const float* __restrict__ bl2,
                                              const float* __restrict__ Wl3, const float* __restrict__ bl3,
                                              const float* __restrict__ Wl, const float* __restrict__ bl,
                                              float* __restrict__ out) {
  __shared__ float s0[256];
  __shared__ float s1[128];
  __shared__ float s2[128];
  int b = blockIdx.x, t = threadIdx.x;
  s0[t] = mono2f(g[b * 256 + t]);
  __syncthreads();
  if (t < 128) {
    float acc = bl2[t];
    for (int k = 0; k < 256; ++k) acc += s0[k] * Wl2[k * 128 + t];
    s1[t] = fmaxf(acc, 0.0f);
  }
  __syncthreads();
  if (t < 128) {
    float acc = bl3[t];
    for (int k = 0; k < 128; ++k) acc += s1[k] * Wl3[k * 128 + t];
    s2[t] = fmaxf(acc, 0.0f);
  }
  __syncthreads();
  if (t < 10) {
    float acc = bl[t];
    for (int k = 0; k < 128; ++k) acc += s2[k] * Wl[k * 10 + t];
    out[b * 10 + t] = acc;
  }
}

extern "C" void kernel_launch(void* const* d_in, const int* in_sizes, int n_in,
                              void* d_out, int out_size, void* d_ws, size_t ws_size,
                              hipStream_t stream) {
  const float* x   = (const float*)d_in[0];
  const int* eidx  = (const int*)d_in[1];
  const int* batch = (const int*)d_in[2];
  const float* W1 = (const float*)d_in[3];   const float* b1 = (const float*)d_in[4];
  const float* W2 = (const float*)d_in[5];   const float* b2 = (const float*)d_in[6];
  const float* W3 = (const float*)d_in[7];   const float* b3 = (const float*)d_in[8];
  const float* W4 = (const float*)d_in[9];   const float* b4 = (const float*)d_in[10];
  const float* Wl2 = (const float*)d_in[11]; const float* bl2 = (const float*)d_in[12];
  const float* Wl3 = (const float*)d_in[13]; const float* bl3 = (const float*)d_in[14];
  const float* Wl  = (const float*)d_in[15]; const float* bl  = (const float*)d_in[16];
  float* out = (float*)d_out;

  // ---- workspace carve ----
  _Float16* bufA = (_Float16*)d_ws;                                // NN*256 fp16
  _Float16* bufB = bufA + (size_t)NN * 256;                        // NN*256 fp16
  int* cnt  = (int*)(bufB + (size_t)NN * 256);                     // NN
  float* dinv = (float*)(cnt + NN);                                // NN
  u16* col  = (u16*)(dinv + NN);                                   // NN*CAP ushort
  unsigned* g = (unsigned*)(col + (size_t)NN * CAP);               // NG*256
  _Float16* W2h = (_Float16*)(g + NG * 256);                       // 256*128
  _Float16* W2l = W2h + 256 * 128;
  _Float16* W3h = W2l + 256 * 128;                                 // 256*256
  _Float16* W3l = W3h + 256 * 256;
  _Float16* W4h = W3l + 256 * 256;
  _Float16* W4l = W4h + 256 * 256;
  float* xs = (float*)bufA;        // NN*9 fp32, dead before k_gemm9 writes bufA
  float* agg9out = (float*)bufB;   // NN*9 fp32, dead before k_agg128 writes bufB

  const int* src = eidx;
  const int* dst = eidx + NE;

  hipMemsetAsync(cnt, 0, NN * sizeof(int), stream);

  k_count<<<(NE + 255) / 256, 256, 0, stream>>>(src, dst, cnt, col);
  k_dinv<<<(NN + 255) / 256, 256, 0, stream>>>(cnt, dinv, x, xs, g);

  k_splitw3<<<(128 * 256 + 2 * 256 * 256 + 255) / 256, 256, 0, stream>>>(
      W2, W3, W4, W2h, W2l, W3h, W3l, W4h, W4l);

  // layer 1: agg 9-dim fp32, GEMM 9->128 (+relu, *dinv, fp16 out to bufA)
  k_agg9<<<(NN + 15) / 16, 256, 0, stream>>>(xs, agg9out, cnt, col, dinv);
  k_gemm9<<<NN / 2, 256, 0, stream>>>(agg9out, W1, b1, dinv, bufA);

  // agg grids: agg128 = 4 nodes/wave (16-lane quarters), agg256 = 2 nodes/wave (32-lane halves)
  int agg128Grid = (((NN + 3) / 4) * 64 + 255) / 256;
  int agg256Grid = (((NN + 1) / 2) * 64 + 255) / 256;
  const int mmGrid = 784;                      // 392 row-blocks x 2 col-blocks, XCD-paired

  // layer 2: gather 128-dim bufA->bufB, MFMA GEMM 128->256 bufB->bufA
  k_agg128<<<agg128Grid, 256, 0, stream>>>((const f16x8*)bufA, (f16x8*)bufB, cnt, col, dinv);
  k_mm<<<mmGrid, 256, 0, stream>>>(bufB, W2h, W2l, b2, bufA, dinv, batch, g, NN, 128, 256, 1);

  // layer 3: gather 256-dim bufA->bufB, GEMM bufB->bufA
  k_agg256<<<agg256Grid, 256, 0, stream>>>((const f16x8*)bufA, (f16x8*)bufB, cnt, col, dinv);
  k_mm<<<mmGrid, 256, 0, stream>>>(bufB, W3h, W3l, b3, bufA, dinv, batch, g, NN, 256, 256, 1);

  // layer 4: gather 256-dim bufA->bufB, GEMM + fused max-pool (no C write)
  k_agg256<<<agg256Grid, 256, 0, stream>>>((const f16x8*)bufA, (f16x8*)bufB, cnt, col, dinv);
  k_mm<<<mmGrid, 256, 0, stream>>>(bufB, W4h, W4l, b4, bufA, dinv, batch, g, NN, 256, 256, 2);

  // head
  k_head<<<NG, 256, 0, stream>>>(g, Wl2, bl2, Wl3, bl3, Wl, bl, out);
}